// Round 1
// baseline (782.086 us; speedup 1.0000x reference)
//
#include <hip/hip_runtime.h>
#include <hip/hip_bf16.h>

// SymbolicGNN: 2-layer edge-MLP message passing + scatter-add + mean-pool + linear head.
// h (fp32) ping-pongs in d_ws. Edge kernel: 32-edge tile/block, 4 waves split N=128,
// bf16 MFMA (16x16x32) with weights in register fragments, exact-erf GELU,
// fp32 atomicAdd scatter.

#define N_NODES 100000
#define NV_ELEMS (N_NODES * 64)
#define N_EDGES 1000000
#define ES 64
#define TILE 32
#define NTILES (N_EDGES / TILE)

typedef __bf16 bf16x8 __attribute__((ext_vector_type(8)));
typedef __bf16 bf16x4 __attribute__((ext_vector_type(4)));
typedef float f32x4 __attribute__((ext_vector_type(4)));

__device__ __forceinline__ f32x4 mfma_16x16x32(bf16x8 a, bf16x8 b, f32x4 c) {
    return __builtin_amdgcn_mfma_f32_16x16x32_bf16(a, b, c, 0, 0, 0);
}

__global__ void k_init(const float* __restrict__ sym, float* __restrict__ h0,
                       float* __restrict__ h1, float* __restrict__ pooled) {
    const int total4 = NV_ELEMS / 4;
    const float4* s4 = (const float4*)sym;
    float4* a4 = (float4*)h0;
    float4* b4 = (float4*)h1;
    for (int i = blockIdx.x * blockDim.x + threadIdx.x; i < total4;
         i += gridDim.x * blockDim.x) {
        float4 v = s4[i];
        a4[i] = v;
        b4[i] = v;
    }
    if (blockIdx.x == 0 && threadIdx.x < ES) pooled[threadIdx.x] = 0.0f;
}

__global__ void k_copy(const float* __restrict__ src, float* __restrict__ dst) {
    const int total4 = NV_ELEMS / 4;
    const float4* s4 = (const float4*)src;
    float4* d4 = (float4*)dst;
    for (int i = blockIdx.x * blockDim.x + threadIdx.x; i < total4;
         i += gridDim.x * blockDim.x) {
        d4[i] = s4[i];
    }
}

// One block = one 32-edge tile (grid-stride). 4 waves: wave w owns hmid cols [32w,32w+32).
__global__ __launch_bounds__(256, 2) void k_edges(
    const int* __restrict__ subj, const int* __restrict__ pred, const int* __restrict__ obj,
    const float* __restrict__ hsrc, float* __restrict__ hdst,
    const float* __restrict__ eemb,
    const float* __restrict__ w1, const float* __restrict__ b1,
    const float* __restrict__ w2, const float* __restrict__ b2) {
    // X: 32 x 192 bf16, stride padded to 200 (row*400B: banks spread 4/row, b128-aligned)
    __shared__ __bf16 sX[TILE][200];
    __shared__ __bf16 sHm[4][TILE][40];   // per-wave hmid slice, 32x32, stride 40
    __shared__ float  sMsum[4][TILE * 65]; // per-wave partial msg, stride 65 (conflict-free)
    __shared__ int    sS[TILE], sP[TILE], sO[TILE];

    const int tid = threadIdx.x;
    const int w   = tid >> 6;   // wave id 0..3
    const int l   = tid & 63;   // lane
    const int lg  = l >> 4;     // k-group 0..3
    const int lc  = l & 15;     // row/col within 16

    // ---- preload weight fragments into registers (amortized over grid-stride tiles) ----
    // B-frag convention: lane l holds B[k = kblk + lg*8 + i][col = l&15]; A uses the same
    // k-assignment, so any hardware per-lane K permutation cancels (sum over k invariant).
    bf16x8 wb1[6][2];
#pragma unroll
    for (int kt = 0; kt < 6; ++kt)
#pragma unroll
        for (int nt = 0; nt < 2; ++nt) {
            bf16x8 f;
#pragma unroll
            for (int i = 0; i < 8; ++i) {
                int k   = kt * 32 + lg * 8 + i;
                int col = w * 32 + nt * 16 + lc;
                f[i] = (__bf16)w1[k * 128 + col];
            }
            wb1[kt][nt] = f;
        }
    bf16x8 wb2[4];
#pragma unroll
    for (int nt = 0; nt < 4; ++nt) {
        bf16x8 f;
#pragma unroll
        for (int i = 0; i < 8; ++i) {
            int k = w * 32 + lg * 8 + i;  // this wave's K-slice of W2
            f[i] = (__bf16)w2[k * 64 + nt * 16 + lc];
        }
        wb2[nt] = f;
    }
    const float b1c0 = b1[w * 32 + lc];
    const float b1c1 = b1[w * 32 + 16 + lc];
    const int scol  = tid & 63;       // scatter col (constant per thread)
    const int srow0 = tid >> 6;
    const float b2v = b2[scol];

    for (int tile = blockIdx.x; tile < NTILES; tile += gridDim.x) {
        const int e0 = tile * TILE;
        if (tid < TILE) {
            sS[tid] = subj[e0 + tid];
            sP[tid] = pred[e0 + tid];
            sO[tid] = obj[e0 + tid];
        }
        __syncthreads();

        // ---- gather X = [h[subj] | e | h[obj]] -> bf16 LDS ----
        {
            const int g16 = tid >> 4, lane16 = tid & 15;
#pragma unroll
            for (int it = 0; it < 6; ++it) {
                int seg  = it * 16 + g16;      // 0..95 = 32 rows x 3 parts
                int row  = seg / 3;
                int part = seg - row * 3;
                const float* src;
                if (part == 0)      src = hsrc + sS[row] * ES;
                else if (part == 1) src = eemb + sP[row] * ES;
                else                src = hsrc + sO[row] * ES;
                float4 v = *(const float4*)(src + lane16 * 4);
                bf16x4 pk;
                pk[0] = (__bf16)v.x; pk[1] = (__bf16)v.y;
                pk[2] = (__bf16)v.z; pk[3] = (__bf16)v.w;
                *(bf16x4*)&sX[row][part * 64 + lane16 * 4] = pk;
            }
        }
        __syncthreads();

        // ---- GEMM1: (32x192) @ W1 -> this wave's 32x32 slice of hmid ----
        f32x4 acc1[2][2];
#pragma unroll
        for (int mt = 0; mt < 2; ++mt)
#pragma unroll
            for (int nt = 0; nt < 2; ++nt) acc1[mt][nt] = (f32x4){0.f, 0.f, 0.f, 0.f};
#pragma unroll
        for (int kt = 0; kt < 6; ++kt) {
#pragma unroll
            for (int mt = 0; mt < 2; ++mt) {
                bf16x8 a = *(const bf16x8*)&sX[mt * 16 + lc][kt * 32 + lg * 8];
                acc1[mt][0] = mfma_16x16x32(a, wb1[kt][0], acc1[mt][0]);
                acc1[mt][1] = mfma_16x16x32(a, wb1[kt][1], acc1[mt][1]);
            }
        }

        // ---- bias + exact GELU -> per-wave hmid LDS (C-layout: row=(l>>4)*4+r, col=l&15) ----
#pragma unroll
        for (int mt = 0; mt < 2; ++mt)
#pragma unroll
            for (int nt = 0; nt < 2; ++nt) {
                float bias = nt ? b1c1 : b1c0;
#pragma unroll
                for (int r = 0; r < 4; ++r) {
                    float v = acc1[mt][nt][r] + bias;
                    float g = 0.5f * v * (1.0f + erff(v * 0.70710678118f));
                    sHm[w][mt * 16 + lg * 4 + r][nt * 16 + lc] = (__bf16)g;
                }
            }

        // ---- GEMM2: this wave's hmid slice @ its W2 K-slice -> partial msg (32x64) ----
        // same-wave LDS dependency (write->read); compiler inserts lgkmcnt waits.
        f32x4 acc2[2][4];
#pragma unroll
        for (int mt = 0; mt < 2; ++mt)
#pragma unroll
            for (int nt = 0; nt < 4; ++nt) acc2[mt][nt] = (f32x4){0.f, 0.f, 0.f, 0.f};
#pragma unroll
        for (int mt = 0; mt < 2; ++mt) {
            bf16x8 a = *(const bf16x8*)&sHm[w][mt * 16 + lc][lg * 8];
#pragma unroll
            for (int nt = 0; nt < 4; ++nt)
                acc2[mt][nt] = mfma_16x16x32(a, wb2[nt], acc2[mt][nt]);
        }
#pragma unroll
        for (int mt = 0; mt < 2; ++mt)
#pragma unroll
            for (int nt = 0; nt < 4; ++nt)
#pragma unroll
                for (int r = 0; r < 4; ++r)
                    sMsum[w][(mt * 16 + lg * 4 + r) * 65 + nt * 16 + lc] = acc2[mt][nt][r];
        __syncthreads();

        // ---- reduce 4 partials + b2, scatter-add to hdst[obj] ----
#pragma unroll
        for (int i = 0; i < 8; ++i) {
            int row = i * 4 + srow0;
            int o   = row * 65 + scol;
            float val = sMsum[0][o] + sMsum[1][o] + sMsum[2][o] + sMsum[3][o] + b2v;
            atomicAdd(&hdst[sO[row] * ES + scol], val);
        }
        __syncthreads();
    }
}

__global__ void k_pool(const float* __restrict__ h, float* __restrict__ pooled) {
    __shared__ float sm[256];
    float acc = 0.f;
    for (int idx = blockIdx.x * 256 + threadIdx.x; idx < NV_ELEMS; idx += gridDim.x * 256)
        acc += h[idx];  // col = idx & 63 stays constant (stride multiple of 64)
    sm[threadIdx.x] = acc;
    __syncthreads();
    if (threadIdx.x < 64) {
        float s = sm[threadIdx.x] + sm[threadIdx.x + 64] + sm[threadIdx.x + 128] +
                  sm[threadIdx.x + 192];
        atomicAdd(&pooled[threadIdx.x], s);
    }
}

__global__ void k_final(const float* __restrict__ pooled, const float* __restrict__ w,
                        const float* __restrict__ b, float* __restrict__ out) {
    __shared__ float sp[64];
    if (threadIdx.x < 64) sp[threadIdx.x] = pooled[threadIdx.x] * (1.0f / N_NODES);
    __syncthreads();
    const int c = threadIdx.x;  // 256 threads = 256 output cols
    float s = b[c];
#pragma unroll
    for (int j = 0; j < 64; ++j) s += sp[j] * w[j * 256 + c];
    out[c] = s;
}

extern "C" void kernel_launch(void* const* d_in, const int* in_sizes, int n_in,
                              void* d_out, int out_size, void* d_ws, size_t ws_size,
                              hipStream_t stream) {
    const int*   subj = (const int*)d_in[0];
    const int*   pred = (const int*)d_in[1];
    const int*   obj  = (const int*)d_in[2];
    const float* sym  = (const float*)d_in[3];
    const float* eemb = (const float*)d_in[4];
    const float* w1   = (const float*)d_in[5];
    const float* b1   = (const float*)d_in[6];
    const float* w2   = (const float*)d_in[7];
    const float* b2   = (const float*)d_in[8];
    const float* lw   = (const float*)d_in[9];
    const float* lb   = (const float*)d_in[10];
    float* out = (float*)d_out;

    float* h0     = (float*)d_ws;
    float* h1     = h0 + (size_t)NV_ELEMS;
    float* pooled = h1 + (size_t)NV_ELEMS;

    // h0 = h1 = sym_emb[0:N] (node ids 0..N-1 < VOCAB so id % V = id); pooled = 0
    k_init<<<2048, 256, 0, stream>>>(sym, h0, h1, pooled);
    // layer 0: gather from h0, scatter into h1 (pre-initialized to h0)
    k_edges<<<1024, 256, 0, stream>>>(subj, pred, obj, h0, h1, eemb,
                                      w1, b1, w2, b2);
    // h0 <- h1 so layer-1 scatter target starts at current h
    k_copy<<<2048, 256, 0, stream>>>(h1, h0);
    // layer 1: gather from h1, scatter into h0
    k_edges<<<1024, 256, 0, stream>>>(subj, pred, obj, h1, h0, eemb,
                                      w1 + 192 * 128, b1 + 128, w2 + 128 * 64, b2 + 64);
    // mean-pool columns of h0, then linear head
    k_pool<<<256, 256, 0, stream>>>(h0, pooled);
    k_final<<<1, 256, 0, stream>>>(pooled, lw, lb, out);
}

// Round 2
// 623.499 us; speedup vs baseline: 1.2543x; 1.2543x over previous
//
#include <hip/hip_runtime.h>
#include <hip/hip_bf16.h>

// SymbolicGNN: 2-layer edge-MLP message passing + scatter-add + mean-pool + linear head.
// h (fp32) ping-pongs in d_ws. Edge kernel: 32-edge tile/block, 4 waves.
// GEMM1: waves split hmid's 128 cols (32 each) -> unified bf16 hmid tile in LDS.
// GEMM2: waves split msg's 64 cols (16 each) with full K=128 -> no cross-wave reduce.
// Fast exact-erf GELU (A&S 7.1.26, |err|<1.5e-7) instead of libm erff.

#define N_NODES 100000
#define NV_ELEMS (N_NODES * 64)
#define N_EDGES 1000000
#define ES 64
#define TILE 32
#define NTILES (N_EDGES / TILE)

typedef __bf16 bf16x8 __attribute__((ext_vector_type(8)));
typedef __bf16 bf16x4 __attribute__((ext_vector_type(4)));
typedef float f32x4 __attribute__((ext_vector_type(4)));

__device__ __forceinline__ f32x4 mfma_16x16x32(bf16x8 a, bf16x8 b, f32x4 c) {
    return __builtin_amdgcn_mfma_f32_16x16x32_bf16(a, b, c, 0, 0, 0);
}

// GELU with Abramowitz-Stegun 7.1.26 erf (max abs err 1.5e-7 in erf).
// Uses HW v_rcp/v_exp instead of libm erff's branchy expansion.
__device__ __forceinline__ float gelu_fast(float v) {
    float u  = fabsf(v) * 0.70710678118654752f;          // |v|/sqrt(2)
    float t  = __builtin_amdgcn_rcpf(fmaf(0.3275911f, u, 1.0f));
    float e  = __expf(-u * u);                            // native v_exp path
    float p  = t * fmaf(t, fmaf(t, fmaf(t, fmaf(t, 1.061405429f, -1.453152027f),
                                        1.421413741f), -0.284496736f), 0.254829592f);
    float er = fmaf(-p, e, 1.0f);                         // erf(|u|)
    float s  = (v >= 0.0f) ? er : -er;                    // erf(u)
    return 0.5f * v * (1.0f + s);
}

__global__ void k_init(const float* __restrict__ sym, float* __restrict__ h0,
                       float* __restrict__ h1, float* __restrict__ pooled) {
    const int total4 = NV_ELEMS / 4;
    const float4* s4 = (const float4*)sym;
    float4* a4 = (float4*)h0;
    float4* b4 = (float4*)h1;
    for (int i = blockIdx.x * blockDim.x + threadIdx.x; i < total4;
         i += gridDim.x * blockDim.x) {
        float4 v = s4[i];
        a4[i] = v;
        b4[i] = v;
    }
    if (blockIdx.x == 0 && threadIdx.x < ES) pooled[threadIdx.x] = 0.0f;
}

__global__ void k_copy(const float* __restrict__ src, float* __restrict__ dst) {
    const int total4 = NV_ELEMS / 4;
    const float4* s4 = (const float4*)src;
    float4* d4 = (float4*)dst;
    for (int i = blockIdx.x * blockDim.x + threadIdx.x; i < total4;
         i += gridDim.x * blockDim.x) {
        d4[i] = s4[i];
    }
}

// One block = one 32-edge tile (grid-stride), 4 waves.
__global__ __launch_bounds__(256, 4) void k_edges(
    const int* __restrict__ subj, const int* __restrict__ pred, const int* __restrict__ obj,
    const float* __restrict__ hsrc, float* __restrict__ hdst,
    const float* __restrict__ eemb,
    const float* __restrict__ w1, const float* __restrict__ b1,
    const float* __restrict__ w2, const float* __restrict__ b2) {
    // X: 32 x 192 bf16, stride 200 (400B/row = 4 banks rotation; 2-way on b128 reads = free)
    __shared__ __bf16 sX[TILE][200];                // 12.8 KB
    __shared__ __bf16 sHm[TILE][136];               // 8.7 KB, unified hmid (stride 272B)
    __shared__ int    sS[TILE], sP[TILE], sO[TILE];

    const int tid = threadIdx.x;
    const int w   = tid >> 6;   // wave id 0..3
    const int l   = tid & 63;   // lane
    const int lg  = l >> 4;     // k-group 0..3
    const int lc  = l & 15;     // row/col within 16

    // ---- preload weight fragments (amortized over grid-stride tiles) ----
    // A and B frags use the same per-lane k assignment (k = 32*kt + 8*lg + i), so any
    // HW K-permutation cancels in the dot product.
    bf16x8 wb1[6][2];
#pragma unroll
    for (int kt = 0; kt < 6; ++kt)
#pragma unroll
        for (int nt = 0; nt < 2; ++nt) {
            bf16x8 f;
#pragma unroll
            for (int i = 0; i < 8; ++i) {
                int k   = kt * 32 + lg * 8 + i;
                int col = w * 32 + nt * 16 + lc;
                f[i] = (__bf16)w1[k * 128 + col];
            }
            wb1[kt][nt] = f;
        }
    // GEMM2: wave w owns msg cols [16w, 16w+16), full K=128.
    bf16x8 wb2[4];
#pragma unroll
    for (int kt = 0; kt < 4; ++kt) {
        bf16x8 f;
#pragma unroll
        for (int i = 0; i < 8; ++i) {
            int k = kt * 32 + lg * 8 + i;
            f[i] = (__bf16)w2[k * 64 + w * 16 + lc];
        }
        wb2[kt] = f;
    }
    const float b1c0 = b1[w * 32 + lc];
    const float b1c1 = b1[w * 32 + 16 + lc];
    const int   scol = w * 16 + lc;      // this thread's scatter col
    const float b2v  = b2[scol];

    for (int tile = blockIdx.x; tile < NTILES; tile += gridDim.x) {
        const int e0 = tile * TILE;
        if (tid < TILE) {
            sS[tid] = subj[e0 + tid];
            sP[tid] = pred[e0 + tid];
            sO[tid] = obj[e0 + tid];
        }
        __syncthreads();

        // ---- gather X = [h[subj] | e | h[obj]] -> bf16 LDS ----
        {
            const int g16 = tid >> 4, lane16 = tid & 15;
#pragma unroll
            for (int it = 0; it < 6; ++it) {
                int seg  = it * 16 + g16;      // 0..95 = 32 rows x 3 parts
                int row  = seg / 3;
                int part = seg - row * 3;
                const float* src;
                if (part == 0)      src = hsrc + sS[row] * ES;
                else if (part == 1) src = eemb + sP[row] * ES;
                else                src = hsrc + sO[row] * ES;
                float4 v = *(const float4*)(src + lane16 * 4);
                bf16x4 pk;
                pk[0] = (__bf16)v.x; pk[1] = (__bf16)v.y;
                pk[2] = (__bf16)v.z; pk[3] = (__bf16)v.w;
                *(bf16x4*)&sX[row][part * 64 + lane16 * 4] = pk;
            }
        }
        __syncthreads();

        // ---- GEMM1: (32x192) @ W1 -> this wave's 32x32 slice of hmid ----
        f32x4 acc1[2][2];
#pragma unroll
        for (int mt = 0; mt < 2; ++mt)
#pragma unroll
            for (int nt = 0; nt < 2; ++nt) acc1[mt][nt] = (f32x4){0.f, 0.f, 0.f, 0.f};
#pragma unroll
        for (int kt = 0; kt < 6; ++kt) {
#pragma unroll
            for (int mt = 0; mt < 2; ++mt) {
                bf16x8 a = *(const bf16x8*)&sX[mt * 16 + lc][kt * 32 + lg * 8];
                acc1[mt][0] = mfma_16x16x32(a, wb1[kt][0], acc1[mt][0]);
                acc1[mt][1] = mfma_16x16x32(a, wb1[kt][1], acc1[mt][1]);
            }
        }

        // ---- bias + GELU -> unified hmid LDS (C-layout: row=(l>>4)*4+r, col=l&15) ----
#pragma unroll
        for (int mt = 0; mt < 2; ++mt)
#pragma unroll
            for (int nt = 0; nt < 2; ++nt) {
                float bias = nt ? b1c1 : b1c0;
#pragma unroll
                for (int r = 0; r < 4; ++r) {
                    float g = gelu_fast(acc1[mt][nt][r] + bias);
                    sHm[mt * 16 + lg * 4 + r][w * 32 + nt * 16 + lc] = (__bf16)g;
                }
            }
        __syncthreads();

        // ---- GEMM2: hmid(32x128) @ W2[:, 16w:16w+16] -> msg cols, no reduce needed ----
        f32x4 acc2[2];
        acc2[0] = (f32x4){0.f, 0.f, 0.f, 0.f};
        acc2[1] = (f32x4){0.f, 0.f, 0.f, 0.f};
#pragma unroll
        for (int kt = 0; kt < 4; ++kt) {
#pragma unroll
            for (int mt = 0; mt < 2; ++mt) {
                bf16x8 a = *(const bf16x8*)&sHm[mt * 16 + lc][kt * 32 + lg * 8];
                acc2[mt] = mfma_16x16x32(a, wb2[kt], acc2[mt]);
            }
        }

        // ---- + b2, scatter-add to hdst[obj]: thread owns (4 rows x 1 col) per mt ----
#pragma unroll
        for (int mt = 0; mt < 2; ++mt)
#pragma unroll
            for (int r = 0; r < 4; ++r) {
                int row = mt * 16 + lg * 4 + r;
                atomicAdd(&hdst[sO[row] * ES + scol], acc2[mt][r] + b2v);
            }
        __syncthreads();
    }
}

__global__ void k_pool(const float* __restrict__ h, float* __restrict__ pooled) {
    __shared__ float sm[256];
    float acc = 0.f;
    for (int idx = blockIdx.x * 256 + threadIdx.x; idx < NV_ELEMS; idx += gridDim.x * 256)
        acc += h[idx];  // col = idx & 63 stays constant (stride multiple of 64)
    sm[threadIdx.x] = acc;
    __syncthreads();
    if (threadIdx.x < 64) {
        float s = sm[threadIdx.x] + sm[threadIdx.x + 64] + sm[threadIdx.x + 128] +
                  sm[threadIdx.x + 192];
        atomicAdd(&pooled[threadIdx.x], s);
    }
}

__global__ void k_final(const float* __restrict__ pooled, const float* __restrict__ w,
                        const float* __restrict__ b, float* __restrict__ out) {
    __shared__ float sp[64];
    if (threadIdx.x < 64) sp[threadIdx.x] = pooled[threadIdx.x] * (1.0f / N_NODES);
    __syncthreads();
    const int c = threadIdx.x;  // 256 threads = 256 output cols
    float s = b[c];
#pragma unroll
    for (int j = 0; j < 64; ++j) s += sp[j] * w[j * 256 + c];
    out[c] = s;
}

extern "C" void kernel_launch(void* const* d_in, const int* in_sizes, int n_in,
                              void* d_out, int out_size, void* d_ws, size_t ws_size,
                              hipStream_t stream) {
    const int*   subj = (const int*)d_in[0];
    const int*   pred = (const int*)d_in[1];
    const int*   obj  = (const int*)d_in[2];
    const float* sym  = (const float*)d_in[3];
    const float* eemb = (const float*)d_in[4];
    const float* w1   = (const float*)d_in[5];
    const float* b1   = (const float*)d_in[6];
    const float* w2   = (const float*)d_in[7];
    const float* b2   = (const float*)d_in[8];
    const float* lw   = (const float*)d_in[9];
    const float* lb   = (const float*)d_in[10];
    float* out = (float*)d_out;

    float* h0     = (float*)d_ws;
    float* h1     = h0 + (size_t)NV_ELEMS;
    float* pooled = h1 + (size_t)NV_ELEMS;

    // h0 = h1 = sym_emb[0:N] (node ids 0..N-1 < VOCAB so id % V = id); pooled = 0
    k_init<<<2048, 256, 0, stream>>>(sym, h0, h1, pooled);
    // layer 0: gather from h0, scatter into h1 (pre-initialized to h0)
    k_edges<<<2048, 256, 0, stream>>>(subj, pred, obj, h0, h1, eemb,
                                      w1, b1, w2, b2);
    // h0 <- h1 so layer-1 scatter target starts at current h
    k_copy<<<2048, 256, 0, stream>>>(h1, h0);
    // layer 1: gather from h1, scatter into h0
    k_edges<<<2048, 256, 0, stream>>>(subj, pred, obj, h1, h0, eemb,
                                      w1 + 192 * 128, b1 + 128, w2 + 128 * 64, b2 + 64);
    // mean-pool columns of h0, then linear head
    k_pool<<<256, 256, 0, stream>>>(h0, pooled);
    k_final<<<1, 256, 0, stream>>>(pooled, lw, lb, out);
}